// Round 4
// baseline (315.460 us; speedup 1.0000x reference)
//
#include <hip/hip_runtime.h>
#include <hip/hip_bf16.h>
#include <stdint.h>
#include <math.h>

// ---------------------------------------------------------------------------
// LinkPredictor: out = minmax_norm(E @ E^T)[block-diag strict upper triangle]
// N=16384 (128 graphs x 128), D=512.
// R4: revert to R2 triangular decode (proven 162us); keep staggered swizzle
// (conflicts=0, free); hoist all kb-invariant addressing out of K-loop;
// fuse global min/max into GEMM epilogue via monotone-int atomics.
// ---------------------------------------------------------------------------

typedef __attribute__((ext_vector_type(8))) __bf16 bf16x8;
typedef __attribute__((ext_vector_type(16))) float floatx16;

#define AS1 __attribute__((address_space(1)))
#define AS3 __attribute__((address_space(3)))

static constexpr int DIM   = 512;
static constexpr int NTILE = 128;
static constexpr int NPART = NTILE * (NTILE + 1) / 2;  // 8256 upper-tri tiles

static __device__ __forceinline__ unsigned short f2bf_rne(float f) {
  unsigned int u = __float_as_uint(f);
  u += 0x7fffu + ((u >> 16) & 1u);
  return (unsigned short)(u >> 16);
}

// monotone map float->int so signed-int atomicMin/Max order floats correctly
static __device__ __forceinline__ int fkey(float f) {
  int s = __float_as_int(f);
  return s >= 0 ? s : (s ^ 0x7fffffff);
}
static __device__ __forceinline__ float funkey(int k) {
  return __int_as_float(k >= 0 ? k : (k ^ 0x7fffffff));
}

// bank swizzle: per-row permutation of the 8 16B chunks (conflict-free for
// both 32-row fragment reads and staging)
static __device__ __forceinline__ int swz(int row, int c8) {
  return c8 ^ (row & 7) ^ ((row >> 3) & 7);
}

// ---- kernel 1: fp32 -> bf16 (+ init the global min/max atomic cells) -------
__global__ void k_convert(const float* __restrict__ in,
                          unsigned short* __restrict__ out,
                          int* __restrict__ mmkeys, int n4) {
  int i = blockIdx.x * blockDim.x + threadIdx.x;
  if (i == 0) {
    mmkeys[0] = 0x7fffffff;  // running min key
    mmkeys[1] = 0x80000000;  // running max key
  }
  if (i >= n4) return;
  float4 v = ((const float4*)in)[i];
  ushort4 o;
  o.x = f2bf_rne(v.x); o.y = f2bf_rne(v.y);
  o.z = f2bf_rne(v.z); o.w = f2bf_rne(v.w);
  ((ushort4*)out)[i] = o;
}

// ---- kernel 2: tiled min/max GEMM over upper-triangular 128x128 tiles ------
// 256 thr = 4 waves (2x2), each wave 64x64 via 2x2 of 32x32x16 MFMA, BK=64,
// global_load_lds(16B) staging, all kb-invariant addresses hoisted.
__global__ __launch_bounds__(256, 4) void k_minmax_gemm(
    const unsigned short* __restrict__ E,
    int* __restrict__ mmkeys,
    float* __restrict__ diagblocks) {
  // decode linear upper-triangle index -> (tr, tc), tc >= tr  (R2-proven)
  const int bi = blockIdx.x;
  int tr = (int)((257.0 - sqrt(66049.0 - 8.0 * (double)bi)) * 0.5);
  if (tr < 0) tr = 0;
  if (tr > 127) tr = 127;
  while (tr * (257 - tr) / 2 > bi) --tr;
  while (tr < 127 && (tr + 1) * (256 - tr) / 2 <= bi) ++tr;
  const int tc = tr + (bi - tr * (257 - tr) / 2);

  const int tid = threadIdx.x;
  __shared__ __align__(16) unsigned short lA[128 * 64];
  __shared__ __align__(16) unsigned short lB[128 * 64];
  __shared__ float2 redbuf[4];

  const int w = tid >> 6, lane = tid & 63;
  const int wr = w >> 1, wc = w & 1;           // wave at (wr,wc) of 2x2
  const int l31 = lane & 31;                   // MFMA 32x32 row/col index
  const int kg  = lane >> 5;                   // MFMA k-group (0/1)

  floatx16 acc[2][2] = {};

  // ---- hoisted staging addresses (kb-invariant) ----
  const unsigned short* gBaseA[4];
  const unsigned short* gBaseB[4];
  unsigned short* ldsA[4];
  unsigned short* ldsB[4];
#pragma unroll
  for (int j = 0; j < 4; j++) {
    int cb  = (w * 4 + j) * 64;                // wave-uniform chunk base
    int p   = cb + lane;
    int row = p >> 3, c8 = p & 7;
    int sc8 = swz(row, c8);
    gBaseA[j] = E + (size_t)(tr * 128 + row) * DIM + sc8 * 8;
    gBaseB[j] = E + (size_t)(tc * 128 + row) * DIM + sc8 * 8;
    ldsA[j] = lA + cb * 8;
    ldsB[j] = lB + cb * 8;
  }
  // ---- hoisted fragment bases (kb/ks-invariant) ----
  const unsigned short* aBase[2];
  const unsigned short* bBase[2];
  int aFold[2], bFold[2];
#pragma unroll
  for (int t = 0; t < 2; t++) {
    int ra = wr * 64 + t * 32 + l31;
    int rb = wc * 64 + t * 32 + l31;
    aBase[t] = lA + ra * 64;                   // 8 chunks * 8 shorts
    bBase[t] = lB + rb * 64;
    aFold[t] = (ra & 7) ^ ((ra >> 3) & 7);
    bFold[t] = (rb & 7) ^ ((rb >> 3) & 7);
  }

  for (int kb = 0; kb < 8; kb++) {             // K = 512 = 8 * BK(64)
    const int kOff = kb * 64;
#pragma unroll
    for (int j = 0; j < 4; j++) {
      __builtin_amdgcn_global_load_lds((const AS1 unsigned int*)(gBaseA[j] + kOff),
                                       (AS3 unsigned int*)ldsA[j], 16, 0, 0);
      __builtin_amdgcn_global_load_lds((const AS1 unsigned int*)(gBaseB[j] + kOff),
                                       (AS3 unsigned int*)ldsB[j], 16, 0, 0);
    }
    __syncthreads();

#pragma unroll
    for (int ks = 0; ks < 4; ks++) {           // 4 k-steps of 16
      bf16x8 af[2], bfv[2];
      const int c8 = ks * 2 + kg;
#pragma unroll
      for (int t = 0; t < 2; t++) {
        af[t]  = *(const bf16x8*)(aBase[t] + ((c8 ^ aFold[t]) * 8));
        bfv[t] = *(const bf16x8*)(bBase[t] + ((c8 ^ bFold[t]) * 8));
      }
#pragma unroll
      for (int ti = 0; ti < 2; ti++)
#pragma unroll
        for (int tj = 0; tj < 2; tj++)
          acc[ti][tj] = __builtin_amdgcn_mfma_f32_32x32x16_bf16(
              af[ti], bfv[tj], acc[ti][tj], 0, 0, 0);
    }
    __syncthreads();
  }

  // per-block min/max -> device atomics (monotone-int keys)
  float vmin = 3.4e38f, vmax = -3.4e38f;
#pragma unroll
  for (int ti = 0; ti < 2; ti++)
#pragma unroll
    for (int tj = 0; tj < 2; tj++)
#pragma unroll
      for (int r = 0; r < 16; r++) {
        float v = acc[ti][tj][r];
        vmin = fminf(vmin, v);
        vmax = fmaxf(vmax, v);
      }
#pragma unroll
  for (int m_ = 32; m_ >= 1; m_ >>= 1) {
    vmin = fminf(vmin, __shfl_xor(vmin, m_));
    vmax = fmaxf(vmax, __shfl_xor(vmax, m_));
  }
  if (lane == 0) redbuf[w] = make_float2(vmin, vmax);
  __syncthreads();
  if (tid == 0) {
    float mn = redbuf[0].x, mx = redbuf[0].y;
    for (int i = 1; i < 4; i++) {
      mn = fminf(mn, redbuf[i].x);
      mx = fmaxf(mx, redbuf[i].y);
    }
    atomicMin(&mmkeys[0], fkey(mn));
    atomicMax(&mmkeys[1], fkey(mx));
  }

  // diagonal tile: store raw 128x128 block (symmetric -> transpose-immune)
  if (tr == tc) {
    float* Bout = diagblocks + (size_t)tr * (128 * 128);
#pragma unroll
    for (int ti = 0; ti < 2; ti++) {
#pragma unroll
      for (int tj = 0; tj < 2; tj++) {
        int cbase = wc * 64 + tj * 32 + l31;   // C/D: col = lane & 31
#pragma unroll
        for (int r = 0; r < 16; r++) {
          int row = wr * 64 + ti * 32 + (r & 3) + 8 * (r >> 2) + 4 * kg;
          Bout[row * 128 + cbase] = acc[ti][tj][r];
        }
      }
    }
  }
}

// ---- kernel 3: gather + normalize ------------------------------------------
__global__ __launch_bounds__(256) void k_gather(
    const int* __restrict__ rix, const int* __restrict__ cix,
    const float* __restrict__ blocks, const int* __restrict__ mmkeys,
    float* __restrict__ out, int n) {
  int i = blockIdx.x * blockDim.x + threadIdx.x;
  if (i >= n) return;
  float m   = funkey(mmkeys[0]);
  float M   = funkey(mmkeys[1]);
  float inv = 1.0f / (M - m + 1e-7f);
  int r = rix[i], c = cix[i];
  int g = r >> 7;
  float v = blocks[((size_t)g << 14) + ((r & 127) << 7) + (c & 127)];
  out[i] = (v - m) * inv;
}

// ---------------------------------------------------------------------------
extern "C" void kernel_launch(void* const* d_in, const int* in_sizes, int n_in,
                              void* d_out, int out_size, void* d_ws, size_t ws_size,
                              hipStream_t stream) {
  const float* emb = (const float*)d_in[0];
  const int* rix   = (const int*)d_in[1];
  const int* cix   = (const int*)d_in[2];

  char* ws = (char*)d_ws;
  int* mmkeys         = (int*)ws;                            // 8 B (pad 256)
  unsigned short* Ebf = (unsigned short*)(ws + 256);         // 16 MB
  float* diagblocks   = (float*)(ws + 256 + (16u << 20));    // 8 MB

  int n_elem = in_sizes[0];            // 16384*512
  int n4 = n_elem / 4;
  k_convert<<<(n4 + 255) / 256, 256, 0, stream>>>(emb, Ebf, mmkeys, n4);

  k_minmax_gemm<<<NPART, 256, 0, stream>>>(Ebf, mmkeys, diagblocks);

  k_gather<<<(out_size + 255) / 256, 256, 0, stream>>>(rix, cix, diagblocks,
                                                       mmkeys, (float*)d_out,
                                                       out_size);
}

// Round 5
// 245.165 us; speedup vs baseline: 1.2867x; 1.2867x over previous
//
#include <hip/hip_runtime.h>
#include <hip/hip_bf16.h>
#include <stdint.h>
#include <math.h>

// ---------------------------------------------------------------------------
// LinkPredictor: out = minmax_norm(E @ E^T)[block-diag strict upper triangle]
// N=16384 (128 graphs x 128), D=512.
// R5: full revert to the R2 configuration (proven GEMM 162us = 855 TF, the
// documented plateau for the 2-barrier K-loop structure).
//   - NO __launch_bounds__ min-wave pin (R4: forced 64 VGPR, wrecked schedule)
//   - NO manual address hoisting (compiler's own hoisting is better)
//   - XOR chunk swizzle c8^(row&7): 4-way conflicts measured harmless in R2
//     (conflict fix in R3 gained nothing; conflicts were off critical path)
//   - plain per-block partials + fused reduce/gather (atomics unneeded)
// ---------------------------------------------------------------------------

typedef __attribute__((ext_vector_type(8))) __bf16 bf16x8;
typedef __attribute__((ext_vector_type(16))) float floatx16;

#define AS1 __attribute__((address_space(1)))
#define AS3 __attribute__((address_space(3)))

static constexpr int DIM    = 512;
static constexpr int NTILE  = 128;                    // tiles per side
static constexpr int NPART  = NTILE * (NTILE + 1) / 2; // 8256 upper-tri tiles

static __device__ __forceinline__ unsigned short f2bf_rne(float f) {
  unsigned int u = __float_as_uint(f);
  u += 0x7fffu + ((u >> 16) & 1u);
  return (unsigned short)(u >> 16);
}

// ---- kernel 1: fp32 -> bf16 ------------------------------------------------
__global__ void k_convert(const float* __restrict__ in,
                          unsigned short* __restrict__ out, int n4) {
  int i = blockIdx.x * blockDim.x + threadIdx.x;
  if (i >= n4) return;
  float4 v = ((const float4*)in)[i];
  ushort4 o;
  o.x = f2bf_rne(v.x); o.y = f2bf_rne(v.y);
  o.z = f2bf_rne(v.z); o.w = f2bf_rne(v.w);
  ((ushort4*)out)[i] = o;
}

// ---- kernel 2: tiled min/max GEMM over upper-triangular 128x128 tiles ------
// 256 thr = 4 waves (2x2), each wave 64x64 via 2x2 of 32x32x16 MFMA, BK=64,
// global_load_lds(16B) staging with XOR chunk swizzle.  (R2-proven: 162 us)
__global__ __launch_bounds__(256) void k_minmax_gemm(
    const unsigned short* __restrict__ E,
    float2* __restrict__ partials,
    float* __restrict__ diagblocks) {
  // decode linear upper-triangle index -> (tr, tc), tc >= tr
  const int bi = blockIdx.x;
  int tr = (int)((257.0 - sqrt(66049.0 - 8.0 * (double)bi)) * 0.5);
  if (tr < 0) tr = 0;
  if (tr > 127) tr = 127;
  while (tr * (257 - tr) / 2 > bi) --tr;
  while (tr < 127 && (tr + 1) * (256 - tr) / 2 <= bi) ++tr;
  const int tc = tr + (bi - tr * (257 - tr) / 2);

  const int tid = threadIdx.x;
  __shared__ __align__(16) unsigned short lA[128 * 64];
  __shared__ __align__(16) unsigned short lB[128 * 64];
  __shared__ float2 redbuf[4];

  const int w = tid >> 6, lane = tid & 63;
  const int wr = w >> 1, wc = w & 1;           // wave at (wr,wc) of 2x2
  const int l31 = lane & 31;                   // MFMA 32x32 row/col index
  const int kg  = lane >> 5;                   // MFMA k-group (0/1)

  floatx16 acc[2][2];
#pragma unroll
  for (int i = 0; i < 2; i++)
#pragma unroll
    for (int j = 0; j < 2; j++)
#pragma unroll
      for (int r = 0; r < 16; r++) acc[i][j][r] = 0.f;

  const int rowBaseA = tr * 128;
  const int rowBaseB = tc * 128;

  for (int kb = 0; kb < 8; kb++) {             // K = 512 = 8 * BK(64)
    const int kBase = kb * 64;
    // stage A,B tiles: 128 rows x 8 chunks(16B); (row,c8) slot holds global
    // chunk (row, c8 ^ (row&7))
#pragma unroll
    for (int j = 0; j < 4; j++) {
      int cb  = (w * 4 + j) * 64;              // wave-uniform chunk base
      int p   = cb + lane;
      int row = p >> 3, c8 = p & 7;
      int sc8 = c8 ^ (row & 7);
      const unsigned short* gA = E + (size_t)(rowBaseA + row) * DIM + kBase + sc8 * 8;
      const unsigned short* gB = E + (size_t)(rowBaseB + row) * DIM + kBase + sc8 * 8;
      __builtin_amdgcn_global_load_lds((const AS1 unsigned int*)gA,
                                       (AS3 unsigned int*)(lA + cb * 8), 16, 0, 0);
      __builtin_amdgcn_global_load_lds((const AS1 unsigned int*)gB,
                                       (AS3 unsigned int*)(lB + cb * 8), 16, 0, 0);
    }
    __syncthreads();

#pragma unroll
    for (int ks = 0; ks < 4; ks++) {           // 4 k-steps of 16
      bf16x8 af[2], bfv[2];
      const int c8 = ks * 2 + kg;
#pragma unroll
      for (int ti = 0; ti < 2; ti++) {
        int r = wr * 64 + ti * 32 + l31;
        af[ti] = *(const bf16x8*)(lA + (r * 8 + (c8 ^ (r & 7))) * 8);
      }
#pragma unroll
      for (int tj = 0; tj < 2; tj++) {
        int r = wc * 64 + tj * 32 + l31;
        bfv[tj] = *(const bf16x8*)(lB + (r * 8 + (c8 ^ (r & 7))) * 8);
      }
#pragma unroll
      for (int ti = 0; ti < 2; ti++)
#pragma unroll
        for (int tj = 0; tj < 2; tj++)
          acc[ti][tj] = __builtin_amdgcn_mfma_f32_32x32x16_bf16(
              af[ti], bfv[tj], acc[ti][tj], 0, 0, 0);
    }
    __syncthreads();
  }

  // per-block min/max
  float vmin = 3.4e38f, vmax = -3.4e38f;
#pragma unroll
  for (int ti = 0; ti < 2; ti++)
#pragma unroll
    for (int tj = 0; tj < 2; tj++)
#pragma unroll
      for (int r = 0; r < 16; r++) {
        float v = acc[ti][tj][r];
        vmin = fminf(vmin, v);
        vmax = fmaxf(vmax, v);
      }
#pragma unroll
  for (int m_ = 32; m_ >= 1; m_ >>= 1) {
    vmin = fminf(vmin, __shfl_xor(vmin, m_));
    vmax = fmaxf(vmax, __shfl_xor(vmax, m_));
  }
  if (lane == 0) redbuf[w] = make_float2(vmin, vmax);
  __syncthreads();
  if (tid == 0) {
    float mn = redbuf[0].x, mx = redbuf[0].y;
    for (int i = 1; i < 4; i++) {
      mn = fminf(mn, redbuf[i].x);
      mx = fmaxf(mx, redbuf[i].y);
    }
    partials[bi] = make_float2(mn, mx);
  }

  // diagonal tile: store raw 128x128 block (symmetric -> transpose-immune)
  if (tr == tc) {
    float* Bout = diagblocks + (size_t)tr * (128 * 128);
#pragma unroll
    for (int ti = 0; ti < 2; ti++) {
#pragma unroll
      for (int tj = 0; tj < 2; tj++) {
        int cbase = wc * 64 + tj * 32 + l31;   // C/D: col = lane & 31
#pragma unroll
        for (int r = 0; r < 16; r++) {
          int row = wr * 64 + ti * 32 + (r & 3) + 8 * (r >> 2) + 4 * kg;
          Bout[row * 128 + cbase] = acc[ti][tj][r];
        }
      }
    }
  }
}

// ---- kernel 3: fused global min/max reduce + gather + normalize ------------
__global__ __launch_bounds__(256) void k_finish(
    const float2* __restrict__ partials,
    const int* __restrict__ rix, const int* __restrict__ cix,
    const float* __restrict__ blocks, float* __restrict__ out, int n) {
  const int tid = threadIdx.x;
  float mn = 3.4e38f, mx = -3.4e38f;
  for (int i = tid; i < NPART; i += 256) {
    float2 p = partials[i];
    mn = fminf(mn, p.x);
    mx = fmaxf(mx, p.y);
  }
#pragma unroll
  for (int m_ = 32; m_ >= 1; m_ >>= 1) {
    mn = fminf(mn, __shfl_xor(mn, m_));
    mx = fmaxf(mx, __shfl_xor(mx, m_));
  }
  __shared__ float2 red[4];
  __shared__ float bcast[2];
  int w = tid >> 6, lane = tid & 63;
  if (lane == 0) red[w] = make_float2(mn, mx);
  __syncthreads();
  if (tid == 0) {
    for (int i = 1; i < 4; i++) {
      mn = fminf(mn, red[i].x);
      mx = fmaxf(mx, red[i].y);
    }
    bcast[0] = mn;
    bcast[1] = 1.0f / (mx - mn + 1e-7f);
  }
  __syncthreads();
  const float m = bcast[0], inv = bcast[1];

  const int stride = gridDim.x * blockDim.x;
  for (int i = blockIdx.x * blockDim.x + tid; i < n; i += stride) {
    int r = rix[i], c = cix[i];
    int g = r >> 7;
    float v = blocks[((size_t)g << 14) + ((r & 127) << 7) + (c & 127)];
    out[i] = (v - m) * inv;
  }
}

// ---------------------------------------------------------------------------
extern "C" void kernel_launch(void* const* d_in, const int* in_sizes, int n_in,
                              void* d_out, int out_size, void* d_ws, size_t ws_size,
                              hipStream_t stream) {
  const float* emb = (const float*)d_in[0];
  const int* rix   = (const int*)d_in[1];
  const int* cix   = (const int*)d_in[2];

  char* ws = (char*)d_ws;
  unsigned short* Ebf = (unsigned short*)(ws + 256);                      // 16 MB
  float2* partials    = (float2*)(ws + 256 + (16u << 20));                // 66 KB (pad 128K)
  float* diagblocks   = (float*)(ws + 256 + (16u << 20) + (128u << 10));  // 8 MB

  int n_elem = in_sizes[0];            // 16384*512
  int n4 = n_elem / 4;
  k_convert<<<(n4 + 255) / 256, 256, 0, stream>>>(emb, Ebf, n4);

  k_minmax_gemm<<<NPART, 256, 0, stream>>>(Ebf, partials, diagblocks);

  k_finish<<<512, 256, 0, stream>>>(partials, rix, cix, diagblocks,
                                    (float*)d_out, out_size);
}